// Round 1
// baseline (1058.613 us; speedup 1.0000x reference)
//
#include <hip/hip_runtime.h>
#include <hip/hip_bf16.h>
#include <stdint.h>

// ---------------------------------------------------------------------------
// CrossAttentionFusion on MI355X (gfx950)
//   out = concat(LN(eeg + (ecg@Wv1^T+bv1)@Wo1^T+bo1),
//                LN(ecg + (eeg@Wv2^T+bv2)@Wo2^T+bo2)) @ Wf^T + bf
// Strategy: bf16 MFMA for all GEMMs (fp32 accumulate), fused residual+LN.
// ---------------------------------------------------------------------------

#define BROWS 32768
#define DIM   1024

typedef __attribute__((ext_vector_type(8))) __bf16 bf16x8;
typedef __attribute__((ext_vector_type(4))) float  f32x4;

__device__ __forceinline__ unsigned short f32_to_bf16_rne(float f) {
    union { float f; unsigned u; } c{f};
    unsigned r = (c.u >> 16) & 1u;
    return (unsigned short)((c.u + 0x7fffu + r) >> 16);
}
__device__ __forceinline__ float bf16_to_f32(unsigned short u) {
    union { unsigned u; float f; } c{(unsigned)u << 16};
    return c.f;
}

// ---------------- f32 -> bf16 conversion (vectorized, grid-stride) ----------
__global__ __launch_bounds__(256) void convert_f32_bf16(
        const float* __restrict__ src, unsigned short* __restrict__ dst, int n8) {
    int stride = gridDim.x * blockDim.x;
    for (int i = blockIdx.x * blockDim.x + threadIdx.x; i < n8; i += stride) {
        const float4* s = reinterpret_cast<const float4*>(src) + 2 * (size_t)i;
        float4 a = s[0];
        float4 b = s[1];
        uint4 o;
        o.x = (unsigned)f32_to_bf16_rne(a.x) | ((unsigned)f32_to_bf16_rne(a.y) << 16);
        o.y = (unsigned)f32_to_bf16_rne(a.z) | ((unsigned)f32_to_bf16_rne(a.w) << 16);
        o.z = (unsigned)f32_to_bf16_rne(b.x) | ((unsigned)f32_to_bf16_rne(b.y) << 16);
        o.w = (unsigned)f32_to_bf16_rne(b.z) | ((unsigned)f32_to_bf16_rne(b.w) << 16);
        reinterpret_cast<uint4*>(dst)[i] = o;
    }
}

// ---------------- GEMM: C[M,1024] = A[M,K](bf16) @ W[1024,K](bf16)^T + bias -
// 128x128 tile, BK=64, 4 waves each 64x64, mfma_f32_16x16x32_bf16.
// global_load_lds(16B) with source-side XOR swizzle (slot ^= row&7) so the
// ds_read_b128 fragment reads are ~conflict-free (rows are 128B = 32 banks).
template <bool OUT_BF16>
__global__ __launch_bounds__(256) void gemm_bt(
        const unsigned short* __restrict__ A,   // [M,K] bf16
        const unsigned short* __restrict__ W,   // [1024,K] bf16 (row n = k-contiguous)
        const float* __restrict__ bias,         // [1024]
        void* __restrict__ Cout,                // [M,1024] bf16 or f32
        int K) {
    constexpr int BM = 128, BN = 128, BK = 64;
    __shared__ char smem[(BM + BN) * BK * 2];          // 32 KiB
    char* ldsA = smem;
    char* ldsB = smem + BM * BK * 2;                   // +16384

    const int t  = threadIdx.x;
    const int n0 = blockIdx.x * BN;                    // 8 n-tiles
    const int m0 = blockIdx.y * BM;                    // 256 m-tiles

    const int wid  = t >> 6, lane = t & 63;
    const int wm   = (wid >> 1) * 64, wn = (wid & 1) * 64;
    const int lr   = lane & 15, lg = lane >> 4;

    auto stage = [&](int k0) {
        #pragma unroll
        for (int r = 0; r < 4; ++r) {                  // A tile: 16 KiB, 4 rounds
            int off  = r * 4096 + t * 16;
            int row  = off >> 7;                       // 128 B per row
            int slot = (off >> 4) & 7;
            int ss   = slot ^ (row & 7);               // source-side swizzle
            const unsigned short* g = A + (size_t)(m0 + row) * K + k0 + ss * 8;
            __builtin_amdgcn_global_load_lds(
                (const __attribute__((address_space(1))) unsigned int*)g,
                (__attribute__((address_space(3))) unsigned int*)(ldsA + off), 16, 0, 0);
        }
        #pragma unroll
        for (int r = 0; r < 4; ++r) {                  // B tile
            int off  = r * 4096 + t * 16;
            int row  = off >> 7;
            int slot = (off >> 4) & 7;
            int ss   = slot ^ (row & 7);
            const unsigned short* g = W + (size_t)(n0 + row) * K + k0 + ss * 8;
            __builtin_amdgcn_global_load_lds(
                (const __attribute__((address_space(1))) unsigned int*)g,
                (__attribute__((address_space(3))) unsigned int*)(ldsB + off), 16, 0, 0);
        }
    };

    f32x4 acc[4][4];
    const f32x4 fzero = {0.f, 0.f, 0.f, 0.f};
    #pragma unroll
    for (int i = 0; i < 4; ++i)
        #pragma unroll
        for (int j = 0; j < 4; ++j) acc[i][j] = fzero;

    const int NT = K / BK;                             // 16 or 32
    stage(0);
    for (int kt = 0; kt < NT; ++kt) {
        __syncthreads();                               // staging visible (vmcnt drain)
        #pragma unroll
        for (int ks = 0; ks < 2; ++ks) {
            bf16x8 af[4], bfr[4];
            #pragma unroll
            for (int mi = 0; mi < 4; ++mi) {
                int row  = wm + mi * 16 + lr;
                int slot = (ks * 4 + lg) ^ (row & 7);
                af[mi] = *reinterpret_cast<const bf16x8*>(ldsA + row * 128 + slot * 16);
            }
            #pragma unroll
            for (int ni = 0; ni < 4; ++ni) {
                int row  = wn + ni * 16 + lr;
                int slot = (ks * 4 + lg) ^ (row & 7);
                bfr[ni] = *reinterpret_cast<const bf16x8*>(ldsB + row * 128 + slot * 16);
            }
            #pragma unroll
            for (int mi = 0; mi < 4; ++mi)
                #pragma unroll
                for (int ni = 0; ni < 4; ++ni)
                    acc[mi][ni] = __builtin_amdgcn_mfma_f32_16x16x32_bf16(
                        af[mi], bfr[ni], acc[mi][ni], 0, 0, 0);
        }
        __syncthreads();                               // all reads done
        if (kt + 1 < NT) stage((kt + 1) * BK);
    }

    // Epilogue: C/D layout col = lane&15, row = (lane>>4)*4 + reg.
    #pragma unroll
    for (int ni = 0; ni < 4; ++ni) {
        int col   = n0 + wn + ni * 16 + lr;
        float bv  = bias[col];
        #pragma unroll
        for (int mi = 0; mi < 4; ++mi) {
            #pragma unroll
            for (int j = 0; j < 4; ++j) {
                int row = m0 + wm + mi * 16 + lg * 4 + j;
                float v = acc[mi][ni][j] + bv;
                if (OUT_BF16)
                    ((unsigned short*)Cout)[(size_t)row * DIM + col] = f32_to_bf16_rne(v);
                else
                    ((float*)Cout)[(size_t)row * DIM + col] = v;
            }
        }
    }
}

// ---------------- residual + LayerNorm, writes bf16 into fused buffer -------
__global__ __launch_bounds__(256) void ln_residual(
        const float* __restrict__ x,            // [B,1024] f32
        const unsigned short* __restrict__ a,   // [B,1024] bf16 (attended)
        const float* __restrict__ g, const float* __restrict__ beta,
        unsigned short* __restrict__ fused,     // [B,2048] bf16
        int colOff) {
    const int row = blockIdx.x;
    const int t   = threadIdx.x;                // 256 threads, 4 elems each
    float4 xv = reinterpret_cast<const float4*>(x + (size_t)row * DIM)[t];
    uint2  av = reinterpret_cast<const uint2*>(a + (size_t)row * DIM)[t];
    float v[4];
    v[0] = xv.x + bf16_to_f32((unsigned short)(av.x & 0xffff));
    v[1] = xv.y + bf16_to_f32((unsigned short)(av.x >> 16));
    v[2] = xv.z + bf16_to_f32((unsigned short)(av.y & 0xffff));
    v[3] = xv.w + bf16_to_f32((unsigned short)(av.y >> 16));

    float s  = v[0] + v[1] + v[2] + v[3];
    float ss = v[0] * v[0] + v[1] * v[1] + v[2] * v[2] + v[3] * v[3];
    #pragma unroll
    for (int off = 32; off > 0; off >>= 1) {
        s  += __shfl_down(s, off, 64);
        ss += __shfl_down(ss, off, 64);
    }
    __shared__ float red[8];
    if ((t & 63) == 0) { red[t >> 6] = s; red[4 + (t >> 6)] = ss; }
    __syncthreads();
    s  = red[0] + red[1] + red[2] + red[3];
    ss = red[4] + red[5] + red[6] + red[7];

    const float mu   = s * (1.f / DIM);
    const float var  = ss * (1.f / DIM) - mu * mu;
    const float rstd = rsqrtf(var + 1e-5f);

    float4 gv = reinterpret_cast<const float4*>(g)[t];
    float4 bv = reinterpret_cast<const float4*>(beta)[t];
    float y0 = (v[0] - mu) * rstd * gv.x + bv.x;
    float y1 = (v[1] - mu) * rstd * gv.y + bv.y;
    float y2 = (v[2] - mu) * rstd * gv.z + bv.z;
    float y3 = (v[3] - mu) * rstd * gv.w + bv.w;
    uint2 o;
    o.x = (unsigned)f32_to_bf16_rne(y0) | ((unsigned)f32_to_bf16_rne(y1) << 16);
    o.y = (unsigned)f32_to_bf16_rne(y2) | ((unsigned)f32_to_bf16_rne(y3) << 16);
    reinterpret_cast<uint2*>(fused + (size_t)row * 2048 + colOff)[t] = o;
}

// ---------------------------------------------------------------------------
extern "C" void kernel_launch(void* const* d_in, const int* in_sizes, int n_in,
                              void* d_out, int out_size, void* d_ws, size_t ws_size,
                              hipStream_t stream) {
    const float* eeg   = (const float*)d_in[0];
    const float* ecg   = (const float*)d_in[1];
    const float* Wv1   = (const float*)d_in[2];
    const float* bv1   = (const float*)d_in[3];
    const float* Wo1   = (const float*)d_in[4];
    const float* bo1   = (const float*)d_in[5];
    const float* Wv2   = (const float*)d_in[6];
    const float* bv2   = (const float*)d_in[7];
    const float* Wo2   = (const float*)d_in[8];
    const float* bo2   = (const float*)d_in[9];
    const float* g1    = (const float*)d_in[10];
    const float* beta1 = (const float*)d_in[11];
    const float* g2    = (const float*)d_in[12];
    const float* beta2 = (const float*)d_in[13];
    const float* Wf    = (const float*)d_in[14];
    const float* bfv   = (const float*)d_in[15];
    float* out = (float*)d_out;

    const size_t BD = (size_t)BROWS * DIM;             // 33.5M elements
    char* ws = (char*)d_ws;
    size_t off = 0;
    auto alloc = [&](size_t bytes) {
        char* p = ws + off;
        off += (bytes + 255) & ~(size_t)255;
        return p;
    };
    unsigned short* eeg_bf = (unsigned short*)alloc(BD * 2);
    unsigned short* ecg_bf = (unsigned short*)alloc(BD * 2);
    unsigned short* Tbuf   = (unsigned short*)alloc(BD * 2);   // intermediate v-proj
    unsigned short* Abuf   = (unsigned short*)alloc(BD * 2);   // attended (bf16)
    unsigned short* fused  = (unsigned short*)alloc(BD * 4);   // [B,2048] bf16
    unsigned short* Wv1b   = (unsigned short*)alloc((size_t)DIM * DIM * 2);
    unsigned short* Wo1b   = (unsigned short*)alloc((size_t)DIM * DIM * 2);
    unsigned short* Wv2b   = (unsigned short*)alloc((size_t)DIM * DIM * 2);
    unsigned short* Wo2b   = (unsigned short*)alloc((size_t)DIM * DIM * 2);
    unsigned short* Wfb    = (unsigned short*)alloc((size_t)DIM * 2 * DIM * 2);

    // ---- conversions ----
    convert_f32_bf16<<<2048, 256, 0, stream>>>(eeg, eeg_bf, (int)(BD / 8));
    convert_f32_bf16<<<2048, 256, 0, stream>>>(ecg, ecg_bf, (int)(BD / 8));
    convert_f32_bf16<<<512, 256, 0, stream>>>(Wv1, Wv1b, DIM * DIM / 8);
    convert_f32_bf16<<<512, 256, 0, stream>>>(Wo1, Wo1b, DIM * DIM / 8);
    convert_f32_bf16<<<512, 256, 0, stream>>>(Wv2, Wv2b, DIM * DIM / 8);
    convert_f32_bf16<<<512, 256, 0, stream>>>(Wo2, Wo2b, DIM * DIM / 8);
    convert_f32_bf16<<<1024, 256, 0, stream>>>(Wf, Wfb, DIM * 2 * DIM / 8);

    dim3 ggrid(DIM / 128, BROWS / 128);                // (8, 256)

    // ---- path 1: eeg_attended = (ecg@Wv1^T+bv1)@Wo1^T+bo1; LN -> fused[:, :D]
    gemm_bt<true><<<ggrid, 256, 0, stream>>>(ecg_bf, Wv1b, bv1, Tbuf, DIM);
    gemm_bt<true><<<ggrid, 256, 0, stream>>>(Tbuf, Wo1b, bo1, Abuf, DIM);
    ln_residual<<<BROWS, 256, 0, stream>>>(eeg, Abuf, g1, beta1, fused, 0);

    // ---- path 2: ecg_attended = (eeg@Wv2^T+bv2)@Wo2^T+bo2; LN -> fused[:, D:]
    gemm_bt<true><<<ggrid, 256, 0, stream>>>(eeg_bf, Wv2b, bv2, Tbuf, DIM);
    gemm_bt<true><<<ggrid, 256, 0, stream>>>(Tbuf, Wo2b, bo2, Abuf, DIM);
    ln_residual<<<BROWS, 256, 0, stream>>>(ecg, Abuf, g2, beta2, fused, DIM);

    // ---- fusion: out = fused @ Wf^T + bf  (K = 2048, f32 out) ----
    gemm_bt<false><<<ggrid, 256, 0, stream>>>(fused, Wfb, bfv, out, 2 * DIM);
}

// Round 2
// 824.645 us; speedup vs baseline: 1.2837x; 1.2837x over previous
//
#include <hip/hip_runtime.h>
#include <hip/hip_bf16.h>
#include <stdint.h>

// ---------------------------------------------------------------------------
// CrossAttentionFusion on MI355X (gfx950)
//   out = concat(LN(eeg + ecg@Wc1^T + b1'), LN(ecg + eeg@Wc2^T + b2')) @ Wf^T + bf
// where Wc1 = Wo1@Wv1, b1' = Wo1@bv1 + bo1 (algebraic fold of the two
// projection GEMMs; softmax over a single key == 1).
// bf16 MFMA everywhere (fp32 accumulate), fused residual+LN.
// ---------------------------------------------------------------------------

#define BROWS 32768
#define DIM   1024

typedef __attribute__((ext_vector_type(8))) __bf16 bf16x8;
typedef __attribute__((ext_vector_type(4))) float  f32x4;

__device__ __forceinline__ unsigned short f32_to_bf16_rne(float f) {
    union { float f; unsigned u; } c{f};
    unsigned r = (c.u >> 16) & 1u;
    return (unsigned short)((c.u + 0x7fffu + r) >> 16);
}
__device__ __forceinline__ float bf16_to_f32(unsigned short u) {
    union { unsigned u; float f; } c{(unsigned)u << 16};
    return c.f;
}

// ---------------- f32 -> bf16 conversion (vectorized, grid-stride) ----------
__global__ __launch_bounds__(256) void convert_f32_bf16(
        const float* __restrict__ src, unsigned short* __restrict__ dst, int n8) {
    int stride = gridDim.x * blockDim.x;
    for (int i = blockIdx.x * blockDim.x + threadIdx.x; i < n8; i += stride) {
        const float4* s = reinterpret_cast<const float4*>(src) + 2 * (size_t)i;
        float4 a = s[0];
        float4 b = s[1];
        uint4 o;
        o.x = (unsigned)f32_to_bf16_rne(a.x) | ((unsigned)f32_to_bf16_rne(a.y) << 16);
        o.y = (unsigned)f32_to_bf16_rne(a.z) | ((unsigned)f32_to_bf16_rne(a.w) << 16);
        o.z = (unsigned)f32_to_bf16_rne(b.x) | ((unsigned)f32_to_bf16_rne(b.y) << 16);
        o.w = (unsigned)f32_to_bf16_rne(b.z) | ((unsigned)f32_to_bf16_rne(b.w) << 16);
        reinterpret_cast<uint4*>(dst)[i] = o;
    }
}

// ---------------- f32 -> bf16 transposed convert (for Wv^T operand) ---------
__global__ __launch_bounds__(256) void transpose_f32_bf16(
        const float* __restrict__ in, unsigned short* __restrict__ out) {
    __shared__ float tile[32][33];
    const int bx = blockIdx.x * 32, by = blockIdx.y * 32;
    const int tx = threadIdx.x & 31, ty = threadIdx.x >> 5;   // 32x8
    #pragma unroll
    for (int r = 0; r < 32; r += 8)
        tile[ty + r][tx] = in[(size_t)(by + ty + r) * DIM + bx + tx];
    __syncthreads();
    #pragma unroll
    for (int r = 0; r < 32; r += 8)
        out[(size_t)(bx + ty + r) * DIM + by + tx] = f32_to_bf16_rne(tile[tx][ty + r]);
}

// ---------------- folded bias: bout[i] = sum_k W[i,k]*bin[k] + badd[i] ------
__global__ __launch_bounds__(256) void fold_bias(
        const float* __restrict__ W, const float* __restrict__ bin,
        const float* __restrict__ badd, float* __restrict__ bout) {
    const int row = blockIdx.x, t = threadIdx.x;
    float4 w = reinterpret_cast<const float4*>(W + (size_t)row * DIM)[t];
    float4 b = reinterpret_cast<const float4*>(bin)[t];
    float s = w.x * b.x + w.y * b.y + w.z * b.z + w.w * b.w;
    #pragma unroll
    for (int off = 32; off > 0; off >>= 1) s += __shfl_down(s, off, 64);
    __shared__ float red[4];
    if ((t & 63) == 0) red[t >> 6] = s;
    __syncthreads();
    if (t == 0) bout[row] = red[0] + red[1] + red[2] + red[3] + badd[row];
}

// ---------------- GEMM: C[M,1024] = A[M,K](bf16) @ W[1024,K](bf16)^T (+bias)
// 128x128 tile, BK=64, 4 waves each 64x64, mfma_f32_16x16x32_bf16.
// Double-buffered LDS; next tile's global_load_lds issued BEFORE the current
// tile's ds_read+MFMA (T3-min pipeline), one barrier per K-step.
// Source-side XOR swizzle (slot ^= row&7) keeps ds_read_b128 ~conflict-free.
// XCD-aware block mapping: all 8 n-tiles of an m-panel on one XCD (n fastest)
// so the A-panel is fetched from HBM once, served from that XCD's L2.
template <bool OUT_BF16, bool HAS_BIAS>
__global__ __launch_bounds__(256) void gemm_bt(
        const unsigned short* __restrict__ A,   // [M,K] bf16
        const unsigned short* __restrict__ W,   // [1024,K] bf16 (row n = k-contig)
        const float* __restrict__ bias,         // [1024] or nullptr
        void* __restrict__ Cout,                // [M,1024] bf16 or f32
        int K) {
    constexpr int BM = 128, BN = 128, BK = 64;
    constexpr int BUF = (BM + BN) * BK * 2;            // 32 KiB per buffer
    __shared__ char smem[2 * BUF];                     // 64 KiB

    // ---- XCD-aware swizzle: nwg = PM*8, PM%8==0 (PM=8 or 256 here) ----
    const int bid = blockIdx.x;
    const int xcd = bid & 7;
    const int j   = bid >> 3;
    const int ppx = (gridDim.x >> 3) >> 3;             // panels per XCD = PM/8
    const int p   = xcd * ppx + (j >> 3);              // m-panel (n fastest)
    const int nq  = j & 7;                             // n-tile
    const int m0  = p * BM;
    const int n0  = nq * BN;

    const int t    = threadIdx.x;
    const int wid  = t >> 6, lane = t & 63;
    const int wm   = (wid >> 1) * 64, wn = (wid & 1) * 64;
    const int lr   = lane & 15, lg = lane >> 4;

    auto stage = [&](int buf, int k0) {
        char* ldsA = smem + buf * BUF;
        char* ldsB = ldsA + BM * BK * 2;
        #pragma unroll
        for (int r = 0; r < 4; ++r) {                  // A tile: 16 KiB
            int off  = r * 4096 + t * 16;
            int row  = off >> 7;                       // 128 B per row
            int slot = (off >> 4) & 7;
            int ss   = slot ^ (row & 7);
            const unsigned short* g = A + (size_t)(m0 + row) * K + k0 + ss * 8;
            __builtin_amdgcn_global_load_lds(
                (const __attribute__((address_space(1))) unsigned int*)g,
                (__attribute__((address_space(3))) unsigned int*)(ldsA + off), 16, 0, 0);
        }
        #pragma unroll
        for (int r = 0; r < 4; ++r) {                  // B tile
            int off  = r * 4096 + t * 16;
            int row  = off >> 7;
            int slot = (off >> 4) & 7;
            int ss   = slot ^ (row & 7);
            const unsigned short* g = W + (size_t)(n0 + row) * K + k0 + ss * 8;
            __builtin_amdgcn_global_load_lds(
                (const __attribute__((address_space(1))) unsigned int*)g,
                (__attribute__((address_space(3))) unsigned int*)(ldsB + off), 16, 0, 0);
        }
    };

    f32x4 acc[4][4];
    const f32x4 fzero = {0.f, 0.f, 0.f, 0.f};
    #pragma unroll
    for (int i = 0; i < 4; ++i)
        #pragma unroll
        for (int jj = 0; jj < 4; ++jj) acc[i][jj] = fzero;

    const int NT = K / BK;
    stage(0, 0);
    __syncthreads();                                   // buf0 staged (vmcnt drain)
    for (int kt = 0; kt < NT; ++kt) {
        const int cur = kt & 1;
        if (kt + 1 < NT) stage(cur ^ 1, (kt + 1) * BK);    // prefetch in flight
        char* ldsA = smem + cur * BUF;
        char* ldsB = ldsA + BM * BK * 2;
        #pragma unroll
        for (int ks = 0; ks < 2; ++ks) {
            bf16x8 af[4], bfr[4];
            #pragma unroll
            for (int mi = 0; mi < 4; ++mi) {
                int row  = wm + mi * 16 + lr;
                int slot = (ks * 4 + lg) ^ (row & 7);
                af[mi] = *reinterpret_cast<const bf16x8*>(ldsA + row * 128 + slot * 16);
            }
            #pragma unroll
            for (int ni = 0; ni < 4; ++ni) {
                int row  = wn + ni * 16 + lr;
                int slot = (ks * 4 + lg) ^ (row & 7);
                bfr[ni] = *reinterpret_cast<const bf16x8*>(ldsB + row * 128 + slot * 16);
            }
            #pragma unroll
            for (int mi = 0; mi < 4; ++mi)
                #pragma unroll
                for (int ni = 0; ni < 4; ++ni)
                    acc[mi][ni] = __builtin_amdgcn_mfma_f32_16x16x32_bf16(
                        af[mi], bfr[ni], acc[mi][ni], 0, 0, 0);
        }
        __syncthreads();       // reads of cur done + prefetch into cur^1 landed
    }

    // Epilogue: C/D layout col = lane&15, row = (lane>>4)*4 + reg.
    #pragma unroll
    for (int ni = 0; ni < 4; ++ni) {
        int col   = n0 + wn + ni * 16 + lr;
        float bv  = HAS_BIAS ? bias[col] : 0.f;
        #pragma unroll
        for (int mi = 0; mi < 4; ++mi) {
            #pragma unroll
            for (int jj = 0; jj < 4; ++jj) {
                int row = m0 + wm + mi * 16 + lg * 4 + jj;
                float v = acc[mi][ni][jj] + bv;
                if (OUT_BF16)
                    ((unsigned short*)Cout)[(size_t)row * DIM + col] = f32_to_bf16_rne(v);
                else
                    ((float*)Cout)[(size_t)row * DIM + col] = v;
            }
        }
    }
}

// ---------------- residual + LayerNorm, writes bf16 into fused buffer -------
__global__ __launch_bounds__(256) void ln_residual(
        const float* __restrict__ x,            // [B,1024] f32
        const unsigned short* __restrict__ a,   // [B,1024] bf16 (attended)
        const float* __restrict__ g, const float* __restrict__ beta,
        unsigned short* __restrict__ fused,     // [B,2048] bf16
        int colOff) {
    const int row = blockIdx.x;
    const int t   = threadIdx.x;                // 256 threads, 4 elems each
    float4 xv = reinterpret_cast<const float4*>(x + (size_t)row * DIM)[t];
    uint2  av = reinterpret_cast<const uint2*>(a + (size_t)row * DIM)[t];
    float v[4];
    v[0] = xv.x + bf16_to_f32((unsigned short)(av.x & 0xffff));
    v[1] = xv.y + bf16_to_f32((unsigned short)(av.x >> 16));
    v[2] = xv.z + bf16_to_f32((unsigned short)(av.y & 0xffff));
    v[3] = xv.w + bf16_to_f32((unsigned short)(av.y >> 16));

    float s  = v[0] + v[1] + v[2] + v[3];
    float ss = v[0] * v[0] + v[1] * v[1] + v[2] * v[2] + v[3] * v[3];
    #pragma unroll
    for (int off = 32; off > 0; off >>= 1) {
        s  += __shfl_down(s, off, 64);
        ss += __shfl_down(ss, off, 64);
    }
    __shared__ float red[8];
    if ((t & 63) == 0) { red[t >> 6] = s; red[4 + (t >> 6)] = ss; }
    __syncthreads();
    s  = red[0] + red[1] + red[2] + red[3];
    ss = red[4] + red[5] + red[6] + red[7];

    const float mu   = s * (1.f / DIM);
    const float var  = ss * (1.f / DIM) - mu * mu;
    const float rstd = rsqrtf(var + 1e-5f);

    float4 gv = reinterpret_cast<const float4*>(g)[t];
    float4 bv = reinterpret_cast<const float4*>(beta)[t];
    float y0 = (v[0] - mu) * rstd * gv.x + bv.x;
    float y1 = (v[1] - mu) * rstd * gv.y + bv.y;
    float y2 = (v[2] - mu) * rstd * gv.z + bv.z;
    float y3 = (v[3] - mu) * rstd * gv.w + bv.w;
    uint2 o;
    o.x = (unsigned)f32_to_bf16_rne(y0) | ((unsigned)f32_to_bf16_rne(y1) << 16);
    o.y = (unsigned)f32_to_bf16_rne(y2) | ((unsigned)f32_to_bf16_rne(y3) << 16);
    reinterpret_cast<uint2*>(fused + (size_t)row * 2048 + colOff)[t] = o;
}

// ---------------------------------------------------------------------------
extern "C" void kernel_launch(void* const* d_in, const int* in_sizes, int n_in,
                              void* d_out, int out_size, void* d_ws, size_t ws_size,
                              hipStream_t stream) {
    const float* eeg   = (const float*)d_in[0];
    const float* ecg   = (const float*)d_in[1];
    const float* Wv1   = (const float*)d_in[2];
    const float* bv1   = (const float*)d_in[3];
    const float* Wo1   = (const float*)d_in[4];
    const float* bo1   = (const float*)d_in[5];
    const float* Wv2   = (const float*)d_in[6];
    const float* bv2   = (const float*)d_in[7];
    const float* Wo2   = (const float*)d_in[8];
    const float* bo2   = (const float*)d_in[9];
    const float* g1    = (const float*)d_in[10];
    const float* beta1 = (const float*)d_in[11];
    const float* g2    = (const float*)d_in[12];
    const float* beta2 = (const float*)d_in[13];
    const float* Wf    = (const float*)d_in[14];
    const float* bfv   = (const float*)d_in[15];
    float* out = (float*)d_out;

    const size_t BD = (size_t)BROWS * DIM;
    char* ws = (char*)d_ws;
    size_t off = 0;
    auto alloc = [&](size_t bytes) {
        char* p = ws + off;
        off += (bytes + 255) & ~(size_t)255;
        return p;
    };
    unsigned short* eeg_bf = (unsigned short*)alloc(BD * 2);
    unsigned short* ecg_bf = (unsigned short*)alloc(BD * 2);
    unsigned short* Abuf   = (unsigned short*)alloc(BD * 2);   // attended (bf16)
    unsigned short* fused  = (unsigned short*)alloc(BD * 4);   // [B,2048] bf16
    unsigned short* Wo1b   = (unsigned short*)alloc((size_t)DIM * DIM * 2);
    unsigned short* Wo2b   = (unsigned short*)alloc((size_t)DIM * DIM * 2);
    unsigned short* Wv1t   = (unsigned short*)alloc((size_t)DIM * DIM * 2);
    unsigned short* Wv2t   = (unsigned short*)alloc((size_t)DIM * DIM * 2);
    unsigned short* Wc1b   = (unsigned short*)alloc((size_t)DIM * DIM * 2);
    unsigned short* Wc2b   = (unsigned short*)alloc((size_t)DIM * DIM * 2);
    unsigned short* Wfb    = (unsigned short*)alloc((size_t)DIM * 2 * DIM * 2);
    float*          b1p    = (float*)alloc(DIM * 4);
    float*          b2p    = (float*)alloc(DIM * 4);

    // ---- conversions / small precompute ----
    convert_f32_bf16<<<2048, 256, 0, stream>>>(eeg, eeg_bf, (int)(BD / 8));
    convert_f32_bf16<<<2048, 256, 0, stream>>>(ecg, ecg_bf, (int)(BD / 8));
    convert_f32_bf16<<<512, 256, 0, stream>>>(Wo1, Wo1b, DIM * DIM / 8);
    convert_f32_bf16<<<512, 256, 0, stream>>>(Wo2, Wo2b, DIM * DIM / 8);
    convert_f32_bf16<<<1024, 256, 0, stream>>>(Wf, Wfb, DIM * 2 * DIM / 8);
    dim3 tgrid(DIM / 32, DIM / 32);
    transpose_f32_bf16<<<tgrid, 256, 0, stream>>>(Wv1, Wv1t);
    transpose_f32_bf16<<<tgrid, 256, 0, stream>>>(Wv2, Wv2t);
    fold_bias<<<DIM, 256, 0, stream>>>(Wo1, bv1, bo1, b1p);
    fold_bias<<<DIM, 256, 0, stream>>>(Wo2, bv2, bo2, b2p);

    // ---- Wc = Wo @ Wv  (C[m,n] = sum_k Wo[m,k] * Wv^T[n,k]) ----
    gemm_bt<true, false><<<64, 256, 0, stream>>>(Wo1b, Wv1t, nullptr, Wc1b, DIM);
    gemm_bt<true, false><<<64, 256, 0, stream>>>(Wo2b, Wv2t, nullptr, Wc2b, DIM);

    // ---- path 1: attended = ecg @ Wc1^T + b1'; LN -> fused[:, :D] ----
    gemm_bt<true, true><<<2048, 256, 0, stream>>>(ecg_bf, Wc1b, b1p, Abuf, DIM);
    ln_residual<<<BROWS, 256, 0, stream>>>(eeg, Abuf, g1, beta1, fused, 0);

    // ---- path 2: attended = eeg @ Wc2^T + b2'; LN -> fused[:, D:] ----
    gemm_bt<true, true><<<2048, 256, 0, stream>>>(eeg_bf, Wc2b, b2p, Abuf, DIM);
    ln_residual<<<BROWS, 256, 0, stream>>>(ecg, Abuf, g2, beta2, fused, DIM);

    // ---- fusion: out = fused @ Wf^T + bf  (K = 2048, f32 out) ----
    gemm_bt<false, true><<<2048, 256, 0, stream>>>(fused, Wfb, bfv, out, 2 * DIM);
}